// Round 3
// baseline (402.991 us; speedup 1.0000x reference)
//
#include <hip/hip_runtime.h>

// ---------------------------------------------------------------------------
// StackedLSTMCell: L=2, B=16384, S=512.
//   per layer: z = x@W + h_tm1@U + b ; (i,f,g,o) = split(z)
//              c = sig(f)*c_tm1 + sig(i)*tanh(g) ; h = sig(o)*tanh(c)
//   h_tm1 = prev_c[l], c_tm1 = prev_h[l] (NNI naming swap). x_{l+1} = c_l.
// GEMM: 256x256 tile, BK=64, 8 waves (2M x 4N), 4-phase-per-K-tile schedule.
//   R3: m201 emission discipline — sched_barrier(0) at phase boundaries,
//   explicit post-barrier lgkmcnt(0), lgkmcnt(8) throttle on the 12-read
//   phase, last two K-tiles peeled (branch-free steady loop). The compiler
//   otherwise dissolves the phase interleave around raw s_barrier (rule #18).
// ---------------------------------------------------------------------------

#define B_DIM   16384
#define S_DIM   512
#define K_DIM   1024          // concat K = S (input) + S (recurrent)
#define N_DIM   2048          // 4 gates * S
#define BS      (B_DIM * S_DIM)
#define NT      16            // K tiles of 64

typedef __bf16 bf16x8 __attribute__((ext_vector_type(8)));
typedef float  f32x4  __attribute__((ext_vector_type(4)));

__device__ __forceinline__ void async16(const void* g, void* l) {
    __builtin_amdgcn_global_load_lds(
        (const __attribute__((address_space(1))) void*)g,
        (__attribute__((address_space(3))) void*)l,
        16, 0, 0);
}

__device__ __forceinline__ float sigm(float x) { return 1.f / (1.f + __expf(-x)); }
__device__ __forceinline__ float tanh_f(float x) { return 1.f - 2.f / (__expf(2.f * x) + 1.f); }

// ---------------------------------------------------------------------------
// Repack weights: Wcat[l][new_n][k] (bf16). (unchanged)
// ---------------------------------------------------------------------------
__global__ __launch_bounds__(256) void repack_w(const float* __restrict__ kern,
                                                const float* __restrict__ rker,
                                                __bf16* __restrict__ Wcat) {
    int bid   = blockIdx.x;
    int ntile = bid & 31;
    int kt    = (bid >> 5) & 7;
    int srcm  = (bid >> 8) & 1;
    int l     = bid >> 9;

    __shared__ float tile[64][65];
    const float* src = (srcm ? rker : kern) + l * (S_DIM * N_DIM);
    int k0 = kt * 64, n0 = ntile * 64;
    int t = threadIdx.x;

    for (int i = 0; i < 4; ++i) {
        int lin4 = i * 256 + t;
        int row  = lin4 >> 4;
        int c4   = (lin4 & 15) << 2;
        float4 v = *(const float4*)(src + (k0 + row) * N_DIM + n0 + c4);
        tile[row][c4]     = v.x;
        tile[row][c4 + 1] = v.y;
        tile[row][c4 + 2] = v.z;
        tile[row][c4 + 3] = v.w;
    }
    __syncthreads();

    int gate = n0 >> 9;
    for (int it = 0; it < 2; ++it) {
        int slot = it * 256 + t;
        int c    = slot >> 3;
        int seg  = slot & 7;
        int n    = n0 + c;
        int s    = n & 511;
        int new_n = ((s >> 4) << 6) + (gate << 4) + (s & 15);
        int kc = srcm * 512 + k0 + seg * 8;
        bf16x8 o;
        #pragma unroll
        for (int j = 0; j < 8; ++j) o[j] = (__bf16)tile[seg * 8 + j][c];
        *(bf16x8*)(Wcat + (size_t)(l * N_DIM + new_n) * K_DIM + kc) = o;
    }
}

// ---------------------------------------------------------------------------
// Convert activations to bf16 concat layout. (unchanged)
// ---------------------------------------------------------------------------
__global__ __launch_bounds__(256) void convert_A(const float* __restrict__ x,
                                                 const float* __restrict__ prev_c,
                                                 __bf16* __restrict__ A0,
                                                 __bf16* __restrict__ A1) {
    int id  = blockIdx.x * 256 + threadIdx.x;
    int sec = id >> 20;
    int e   = id & ((1 << 20) - 1);
    int r   = e >> 6;
    int c   = (e & 63) << 3;
    const float* src;
    __bf16* dst;
    if (sec == 0)      { src = x + (size_t)r * S_DIM + c;            dst = A0 + (size_t)r * K_DIM + c; }
    else if (sec == 1) { src = prev_c + (size_t)r * S_DIM + c;       dst = A0 + (size_t)r * K_DIM + 512 + c; }
    else               { src = prev_c + (size_t)BS + (size_t)r * S_DIM + c; dst = A1 + (size_t)r * K_DIM + 512 + c; }
    float4 v0 = *(const float4*)(src);
    float4 v1 = *(const float4*)(src + 4);
    bf16x8 o;
    o[0] = (__bf16)v0.x; o[1] = (__bf16)v0.y; o[2] = (__bf16)v0.z; o[3] = (__bf16)v0.w;
    o[4] = (__bf16)v1.x; o[5] = (__bf16)v1.y; o[6] = (__bf16)v1.z; o[7] = (__bf16)v1.w;
    *(bf16x8*)dst = o;
}

// ---------------------------------------------------------------------------
// Fused GEMM + LSTM cell, 256x256 tile / BK=64 / 8 waves / 4 phases per K-tile.
//
// LDS (128 KiB): buf b (64 KiB): A-half h at b*64K + h*16K (128 rows x 128 B),
// B-half h at b*64K + 32K + h*16K. T2 swizzle: (row r, byte c) stored at
// r*128 + (c ^ ((r&7)<<4)); global_load_lds writes linearly, so SOURCE is
// inverse-swizzled (rule #21).
//
// Phase skeleton (m201 discipline):
//   [ds_reads ; stages] SCHED0 [lgkm throttle if 12 reads] BAR
//   lgkmcnt(0) SCHED0 PRIO1 [16 MFMA] PRIO0 SCHED0 [vmcnt if P3] BAR
// Correctness gates: P2-post-barrier (A(t) reads done) -> P3 STAGE_A(cur)
// legal; P3 VMCNT(4)+BAR (B(t+1),A(t+1) landed, cross-wave) -> t+1 reads.
// ---------------------------------------------------------------------------
__global__ __launch_bounds__(512, 2) void lstm_gemm(const __bf16* __restrict__ A,
                                                    const __bf16* __restrict__ W,
                                                    const float* __restrict__ c_tm1p,
                                                    const float* __restrict__ bias,
                                                    float* __restrict__ outh,
                                                    float* __restrict__ outc,
                                                    __bf16* __restrict__ A_next) {
    __shared__ __align__(16) char smem[131072];

    int tid  = threadIdx.x;
    int w    = tid >> 6, lane = tid & 63;
    int wm   = w >> 2, wn = w & 3;          // 2 x 4 waves
    int l15  = lane & 15, quad = lane >> 4;
    int wh   = wn >> 1, wn1 = wn & 1;

    int bid   = blockIdx.x;
    int rowA0 = (bid & 63) << 8;            // M-major: A streamed once globally
    int rowB0 = (bid >> 6) << 8;            // n-panel changes every 64 blocks

    // ---- staging geometry ----
    int r0   = tid >> 3;                    // 0..63
    int bo   = (tid & 7) << 4;              // 0..112
    int bsrc = bo ^ ((r0 & 7) << 4);        // inverse-swizzled source byte
    const __bf16* aSrc = A + (size_t)(rowA0 + r0) * K_DIM + (bsrc >> 1);
    const __bf16* bSrc = W + (size_t)(rowB0 + r0) * K_DIM + (bsrc >> 1);
    const float*  cSrc = c_tm1p + (size_t)rowA0 * S_DIM + (rowB0 >> 2);
    char* smb = smem;
    int dA0 = tid * 16;

    // ---- fragment-read constants ----
    int arow = l15 * 128;
    int axor = (l15 & 7) << 4;
    int kq0 = (quad * 16) ^ axor;
    int kq1 = (64 + quad * 16) ^ axor;

#define STAGE_A(BUF, H, KO) do { \
    async16(aSrc + (size_t)((H) * 128) * K_DIM + (KO),      smb + (BUF) * 65536 + (H) * 16384 + dA0); \
    async16(aSrc + (size_t)((H) * 128 + 64) * K_DIM + (KO), smb + (BUF) * 65536 + (H) * 16384 + 8192 + dA0); \
} while (0)
#define STAGE_B(BUF, H, KO) do { \
    async16(bSrc + (size_t)((H) * 128) * K_DIM + (KO),      smb + (BUF) * 65536 + 32768 + (H) * 16384 + dA0); \
    async16(bSrc + (size_t)((H) * 128 + 64) * K_DIM + (KO), smb + (BUF) * 65536 + 32768 + (H) * 16384 + 8192 + dA0); \
} while (0)
#define STAGE_C(BUF) do { \
    _Pragma("unroll") \
    for (int ci = 0; ci < 8; ++ci) { \
        int slot_ = ci * 512 + tid; \
        int row_ = slot_ >> 4, seg_ = slot_ & 15; \
        async16(cSrc + (size_t)row_ * S_DIM + seg_ * 4, smb + (BUF) * 65536 + ci * 8192 + dA0); \
    } } while (0)
#define LOAD_A(MH) do { \
    _Pragma("unroll") \
    for (int mt = 0; mt < 4; ++mt) { \
        const char* p_ = Abase + ((MH) * 64 + mt * 16) * 128 + arow; \
        a[mt][0] = *(const bf16x8*)(p_ + kq0); \
        a[mt][1] = *(const bf16x8*)(p_ + kq1); \
    } } while (0)
#define LOAD_B(DST, NH) do { \
    _Pragma("unroll") \
    for (int nt = 0; nt < 2; ++nt) { \
        const char* p_ = Bbase + (wn1 * 64 + (NH) * 32 + nt * 16) * 128 + arow; \
        DST[nt][0] = *(const bf16x8*)(p_ + kq0); \
        DST[nt][1] = *(const bf16x8*)(p_ + kq1); \
    } } while (0)
#define MFMA_Q(MH, NH, BB) do { \
    _Pragma("unroll") \
    for (int mt = 0; mt < 4; ++mt) \
    _Pragma("unroll") \
    for (int nt = 0; nt < 2; ++nt) { \
        acc[MH][NH][mt][nt] = __builtin_amdgcn_mfma_f32_16x16x32_bf16(a[mt][0], BB[nt][0], acc[MH][NH][mt][nt], 0, 0, 0); \
        acc[MH][NH][mt][nt] = __builtin_amdgcn_mfma_f32_16x16x32_bf16(a[mt][1], BB[nt][1], acc[MH][NH][mt][nt], 0, 0, 0); \
    } } while (0)
#define SCHED0 __builtin_amdgcn_sched_barrier(0)
#define BAR    __builtin_amdgcn_s_barrier()
#define PRIO1  __builtin_amdgcn_s_setprio(1)
#define PRIO0  __builtin_amdgcn_s_setprio(0)
#define LGKM0  do { asm volatile("s_waitcnt lgkmcnt(0)" ::: "memory"); SCHED0; } while (0)
#define LGKM8  do { asm volatile("s_waitcnt lgkmcnt(8)" ::: "memory"); SCHED0; } while (0)
#define VMCNT(N) do { asm volatile("s_waitcnt vmcnt(" #N ")" ::: "memory"); SCHED0; } while (0)

    f32x4 acc[2][2][4][2];                  // [mh][nh][mt][nt]
    #pragma unroll
    for (int i = 0; i < 2; ++i)
        #pragma unroll
        for (int j = 0; j < 2; ++j)
            #pragma unroll
            for (int mt = 0; mt < 4; ++mt)
                #pragma unroll
                for (int nt = 0; nt < 2; ++nt)
                    acc[i][j][mt][nt] = (f32x4){0.f, 0.f, 0.f, 0.f};

    bf16x8 a[4][2], b0[2][2], b1[2][2];
    const char *Abase, *Bbase;

    // ---- prologue: tile 0 (8 loads) + tile 1's A pair ----
    STAGE_A(0, 0, 0); STAGE_A(0, 1, 0);
    STAGE_B(0, 0, 0); STAGE_B(0, 1, 0);
    STAGE_A(1, 0, 64); STAGE_A(1, 1, 64);
    SCHED0;
    VMCNT(4);                               // tile 0 resident; A(1) in flight
    BAR;

    // ---- steady state: t = 0 .. NT-3, branch-free ----
    for (int t = 0; t < NT - 2; ++t) {
        int cur = t & 1, nxt = cur ^ 1;
        Abase = smb + cur * 65536 + wm * 16384;
        Bbase = smb + cur * 65536 + 32768 + wh * 16384;
        int ka = (t + 1) * 64, kb = (t + 2) * 64;

        // P0: quadrant (0,0) — 12 ds_reads
        LOAD_A(0); LOAD_B(b0, 0);
        STAGE_B(nxt, 0, ka);
        SCHED0; LGKM8; BAR;
        LGKM0; PRIO1; MFMA_Q(0, 0, b0); PRIO0; SCHED0; BAR;

        // P1: quadrant (0,1) — 4 ds_reads
        LOAD_B(b1, 1);
        STAGE_B(nxt, 1, ka);
        SCHED0; BAR;
        LGKM0; PRIO1; MFMA_Q(0, 1, b1); PRIO0; SCHED0; BAR;

        // P2: quadrant (1,1) — 8 ds_reads
        LOAD_A(1);
        SCHED0; BAR;
        LGKM0; PRIO1; MFMA_Q(1, 1, b1); PRIO0; SCHED0; BAR;

        // P3: quadrant (1,0) — 0 ds_reads; A(t+2) prefetch
        STAGE_A(cur, 0, kb); STAGE_A(cur, 1, kb);
        SCHED0; BAR;
        PRIO1; MFMA_Q(1, 0, b0); PRIO0; SCHED0;
        VMCNT(4);                           // tile t+1 resident; A(t+2) in flight
        BAR;
    }

    // ---- t = NT-2: no A prefetch; drain all staging ----
    {
        Abase = smb + 0 * 65536 + wm * 16384;       // (NT-2)&1 == 0
        Bbase = smb + 0 * 65536 + 32768 + wh * 16384;
        int ka = (NT - 1) * 64;

        LOAD_A(0); LOAD_B(b0, 0);
        STAGE_B(1, 0, ka);
        SCHED0; LGKM8; BAR;
        LGKM0; PRIO1; MFMA_Q(0, 0, b0); PRIO0; SCHED0; BAR;

        LOAD_B(b1, 1);
        STAGE_B(1, 1, ka);
        SCHED0; BAR;
        LGKM0; PRIO1; MFMA_Q(0, 1, b1); PRIO0; SCHED0; BAR;

        LOAD_A(1);
        SCHED0; BAR;
        LGKM0; PRIO1; MFMA_Q(1, 1, b1); PRIO0; SCHED0; BAR;

        SCHED0; BAR;
        PRIO1; MFMA_Q(1, 0, b0); PRIO0; SCHED0;
        VMCNT(0);                           // last staged tile fully resident
        BAR;
    }

    // ---- t = NT-1: stage c_tm1 into dead buf0 during P0 ----
    {
        Abase = smb + 1 * 65536 + wm * 16384;       // (NT-1)&1 == 1
        Bbase = smb + 1 * 65536 + 32768 + wh * 16384;

        LOAD_A(0); LOAD_B(b0, 0);
        STAGE_C(0);
        SCHED0; LGKM8; BAR;
        LGKM0; PRIO1; MFMA_Q(0, 0, b0); PRIO0; SCHED0; BAR;

        LOAD_B(b1, 1);
        SCHED0; BAR;
        LGKM0; PRIO1; MFMA_Q(0, 1, b1); PRIO0; SCHED0; BAR;

        LOAD_A(1);
        SCHED0; BAR;
        LGKM0; PRIO1; MFMA_Q(1, 1, b1); PRIO0; SCHED0; BAR;

        SCHED0; BAR;
        PRIO1; MFMA_Q(1, 0, b0); PRIO0; SCHED0;
    }

    VMCNT(0);                               // c_tm1 DMA complete
    BAR;

    // ---- epilogue: lane-local LSTM cell; c_tm1 from LDS (buf0) ----
    const float* cLds = (const float*)smb;
    int u    = (((rowB0 >> 6) + wn) << 4) + l15;
    int ccol = wn * 16 + l15;
    float bg0 = bias[0 * S_DIM + u];
    float bg1 = bias[1 * S_DIM + u];
    float bg2 = bias[2 * S_DIM + u];
    float bg3 = bias[3 * S_DIM + u];

    #pragma unroll
    for (int mh = 0; mh < 2; ++mh)
        #pragma unroll
        for (int mt = 0; mt < 4; ++mt) {
            int rloc = wm * 128 + mh * 64 + mt * 16 + quad * 4;
            int Rb   = rowA0 + rloc;
            #pragma unroll
            for (int reg = 0; reg < 4; ++reg) {
                int R = Rb + reg;
                float zi = acc[mh][0][mt][0][reg] + bg0;
                float zf = acc[mh][0][mt][1][reg] + bg1;
                float zg = acc[mh][1][mt][0][reg] + bg2;
                float zo = acc[mh][1][mt][1][reg] + bg3;
                float ct = cLds[(rloc + reg) * 64 + ccol];
                float cv = sigm(zf) * ct + sigm(zi) * tanh_f(zg);
                float hv = sigm(zo) * tanh_f(cv);
                outh[(size_t)R * S_DIM + u] = hv;
                outc[(size_t)R * S_DIM + u] = cv;
                if (A_next) A_next[(size_t)R * K_DIM + u] = (__bf16)cv;
            }
        }

#undef STAGE_A
#undef STAGE_B
#undef STAGE_C
#undef LOAD_A
#undef LOAD_B
#undef MFMA_Q
#undef SCHED0
#undef BAR
#undef PRIO1
#undef PRIO0
#undef LGKM0
#undef LGKM8
#undef VMCNT
}

// ---------------------------------------------------------------------------
extern "C" void kernel_launch(void* const* d_in, const int* in_sizes, int n_in,
                              void* d_out, int out_size, void* d_ws, size_t ws_size,
                              hipStream_t stream) {
    const float* x      = (const float*)d_in[0];
    const float* prev_c = (const float*)d_in[1];
    const float* prev_h = (const float*)d_in[2];
    const float* kern   = (const float*)d_in[3];
    const float* rker   = (const float*)d_in[4];
    const float* bias   = (const float*)d_in[5];
    float* out = (float*)d_out;

    char* ws = (char*)d_ws;
    __bf16* Wcat = (__bf16*)ws;                              // 8 MB
    __bf16* A0   = (__bf16*)(ws + (size_t)8  * 1024 * 1024); // 32 MB
    __bf16* A1   = (__bf16*)(ws + (size_t)40 * 1024 * 1024); // 32 MB

    convert_A<<<12288, 256, 0, stream>>>(x, prev_c, A0, A1);
    repack_w<<<1024, 256, 0, stream>>>(kern, rker, Wcat);

    // grid: 512 blocks; bid%64 = m-panel (fast), bid/64 = n-panel (slow)
    lstm_gemm<<<512, 512, 0, stream>>>(A0, Wcat,
                                       prev_h,              bias,
                                       out,                 out + (size_t)BS,
                                       A1);
    lstm_gemm<<<512, 512, 0, stream>>>(A1, Wcat + (size_t)N_DIM * K_DIM,
                                       prev_h + (size_t)BS, bias + N_DIM,
                                       out + (size_t)2 * BS, out + (size_t)3 * BS,
                                       nullptr);
}